// Round 6
// baseline (230.367 us; speedup 1.0000x reference)
//
#include <hip/hip_runtime.h>
#include <hip/hip_bf16.h>
#include <stdint.h>

// Cheb graph conv: out[b,o,m,t] = sum_{k,n,c} T_k[n,m] x[b,c,n,t] Theta[k,c,o]
// Folded:  W[(o,m)][(c,n)] = sum_k T_k[n,m] Theta[k,c,o]
//          out_b (768x512) = W @ x_b (768x512) per batch, bf16 MFMA.
// R6: A-fragments fragment-ordered in global (L2-resident, no LDS staging,
// no prefetch regs); Bs double-buffered -> ONE barrier per kt. LDS ops
// 12 -> 6 b128 per wave per kt. VGPR must stay <= 64 (unified file:
// +64 AGPR acc = 128 -> 4 waves/SIMD).

#define NV 24
#define CIN 32
#define COUT 32
#define TDIM 512
#define BATCH 64
#define MDIM 768   // COUT*NV
#define KD 768     // CIN*NV
#define BM 128
#define BN 128
#define BK 32
#define NKT (KD / BK)    // 24
#define NTT (TDIM / BN)  // 4
#define NMT (MDIM / BM)  // 6
#define BSTRIDE 40       // Bs row stride in shorts (80 B, 16B-aligned rows)
#define BSSZ (BN * BSTRIDE)  // 5120 shorts per buffer

typedef __attribute__((ext_vector_type(8))) short short8v;  // 8 bf16
typedef __attribute__((ext_vector_type(4))) float float4v;  // 4 fp32 acc

__device__ inline unsigned short f2bf(float f) {
    unsigned int u = __float_as_uint(f);
    unsigned int r = (u + 0x7fffu + ((u >> 16) & 1u)) >> 16;
    return (unsigned short)r;
}

// ---------------------------------------------------------------------------
// prep_w: writes WF fragment-ordered: idx = ((f*4 + i)*64 + lane)*8 + e,
// f = mw*24 + kt (mw = mt*2+wm). Element (m,k): m = mw*64 + i*16 + (lane&15),
// k = kt*32 + (lane>>4)*8 + e.  Total 589824 shorts = 1.18 MB.
// NV*NV=576 > 256 threads: per-element phases must be strided loops.
__global__ __launch_bounds__(256) void prep_w(const float* __restrict__ adj,
                                              const float* __restrict__ Theta,
                                              unsigned short* __restrict__ WF) {
    __shared__ float adjS[NV * NV];
    __shared__ float disS[NV];
    __shared__ float LS[NV * NV];
    __shared__ float T2S[NV * NV];
    int tid = threadIdx.x;
    for (int e = tid; e < NV * NV; e += 256) adjS[e] = adj[e];
    __syncthreads();
    if (tid < NV) {
        float d = 0.f;
        for (int j = 0; j < NV; ++j) d += adjS[tid * NV + j];
        disS[tid] = (d > 0.f) ? rsqrtf(d) : 0.f;
    }
    __syncthreads();
    for (int e = tid; e < NV * NV; e += 256) {
        int i = e / NV, j = e % NV;
        LS[e] = disS[i] * adjS[j * NV + i] * disS[j];  // L = D^-1/2 A^T D^-1/2
    }
    __syncthreads();
    for (int e = tid; e < NV * NV; e += 256) {
        int i = e / NV, j = e % NV;
        float s = 0.f;
        for (int p = 0; p < NV; ++p) s += LS[i * NV + p] * LS[p * NV + j];
        T2S[e] = 2.f * s - (i == j ? 1.f : 0.f);
    }
    __syncthreads();
    const int TOT = 12 * NKT * 4 * 64 * 8;  // 589824
    for (int idx = blockIdx.x * 256 + tid; idx < TOT; idx += 64 * 256) {
        int e = idx & 7;
        int lane = (idx >> 3) & 63;
        int i = (idx >> 9) & 3;
        int f = idx >> 11;        // 0..287
        int kt = f % NKT;
        int mw = f / NKT;         // 0..11
        int m = mw * 64 + i * 16 + (lane & 15);
        int k = kt * BK + (lane >> 4) * 8 + e;
        int o = m / NV, mv = m % NV;
        int c = k / NV, n = k % NV;
        float th0 = Theta[0 * CIN * COUT + c * COUT + o];
        float th1 = Theta[1 * CIN * COUT + c * COUT + o];
        float th2 = Theta[2 * CIN * COUT + c * COUT + o];
        float v = (n == mv ? th0 : 0.f) + LS[n * NV + mv] * th1 + T2S[n * NV + mv] * th2;
        WF[idx] = f2bf(v);
    }
}

// ---------------------------------------------------------------------------
// gemm_fused: out tile (128m x 128t) = W tile @ x^T tile.
// grid 1536 (XCD-swizzled); 256 thr = 4 waves (2x2 of 64x64).
__global__ __launch_bounds__(256) void gemm_fused(const unsigned short* __restrict__ WF,
                                                  const float* __restrict__ x,
                                                  float* __restrict__ out) {
    __shared__ __attribute__((aligned(16))) unsigned short Bs[2 * BSSZ];  // 20 KB dbuf [t][k]

    // XCD swizzle: the 6 mt-sharers of an x-slice land on one XCD window.
    int id = blockIdx.x;
    int hi = id / 48;
    int rem = id - hi * 48;
    int mt = rem >> 3;               // 0..5
    int g = hi * 8 + (rem & 7);      // 0..255
    int b = g >> 2;
    int tt = g & 3;

    int tid = threadIdx.x;
    int wave = tid >> 6;
    int lane = tid & 63;
    int quad = lane >> 4;
    int l16 = lane & 15;
    int wm = wave >> 1, wn = wave & 1;
    int mw = mt * 2 + wm;
    int kq = wave;      // x-stage: this wave covers k = kq*8 .. kq*8+7
    int tp = lane;      // x-stage: this thread covers t = tp and tp+64

    const float* xb = x + (size_t)b * KD * TDIM + tt * BN;
    // per-wave A-fragment stream: 16 B chunks, chunk = (kt*4 + i)*64 + lane
    const short8v* af = (const short8v*)(WF) + (size_t)mw * NKT * 256 + lane;

    const float4v zero4 = {0.f, 0.f, 0.f, 0.f};
    float4v acc[4][4];
#pragma unroll
    for (int i = 0; i < 4; ++i)
#pragma unroll
        for (int j = 0; j < 4; ++j) acc[i][j] = zero4;

    float Xr[16];

    // prologue: load x(kt=0), pack, write Bs buf0
    {
        const float* xr = xb + (size_t)(kq * 8) * TDIM;
#pragma unroll
        for (int kk = 0; kk < 8; ++kk) {
            Xr[kk] = xr[(size_t)kk * TDIM + tp];
            Xr[8 + kk] = xr[(size_t)kk * TDIM + tp + 64];
        }
        union { short8v s; __hip_bfloat162 h[4]; } u0, u1;
#pragma unroll
        for (int i = 0; i < 4; ++i) {
            u0.h[i] = __float22bfloat162_rn({Xr[2 * i], Xr[2 * i + 1]});
            u1.h[i] = __float22bfloat162_rn({Xr[8 + 2 * i], Xr[8 + 2 * i + 1]});
        }
        *(short8v*)(Bs + tp * BSTRIDE + kq * 8) = u0.s;
        *(short8v*)(Bs + (tp + 64) * BSTRIDE + kq * 8) = u1.s;
    }

    for (int kt = 0; kt < NKT; ++kt) {
        int p = kt & 1;
        __syncthreads();  // lgkm-only drain (no glb_lds anywhere)

        // A fragments straight from L2 (issued early, consumed by MFMA)
        short8v a4[4];
#pragma unroll
        for (int i = 0; i < 4; ++i) a4[i] = af[(kt * 4 + i) * 64];

        // x prefetch for kt+1 (in flight across MFMA; no barrier drains it)
        if (kt + 1 < NKT) {
            const float* xr = xb + (size_t)((kt + 1) * BK + kq * 8) * TDIM;
#pragma unroll
            for (int kk = 0; kk < 8; ++kk) {
                Xr[kk] = xr[(size_t)kk * TDIM + tp];
                Xr[8 + kk] = xr[(size_t)kk * TDIM + tp + 64];
            }
        }

        // B fragments from current buffer
        const unsigned short* bsr = Bs + p * BSSZ;
        short8v bb[4];
#pragma unroll
        for (int j = 0; j < 4; ++j)
            bb[j] = *(const short8v*)(bsr + (wn * 64 + j * 16 + l16) * BSTRIDE + quad * 8);

#pragma unroll
        for (int i = 0; i < 4; ++i)
#pragma unroll
            for (int j = 0; j < 4; ++j)
                acc[i][j] = __builtin_amdgcn_mfma_f32_16x16x32_bf16(a4[i], bb[j], acc[i][j], 0, 0, 0);

        // pack + write NEXT iteration's tile into the other buffer
        if (kt + 1 < NKT) {
            union { short8v s; __hip_bfloat162 h[4]; } u0, u1;
#pragma unroll
            for (int i = 0; i < 4; ++i) {
                u0.h[i] = __float22bfloat162_rn({Xr[2 * i], Xr[2 * i + 1]});
                u1.h[i] = __float22bfloat162_rn({Xr[8 + 2 * i], Xr[8 + 2 * i + 1]});
            }
            unsigned short* bsw = Bs + (p ^ 1) * BSSZ;
            *(short8v*)(bsw + tp * BSTRIDE + kq * 8) = u0.s;
            *(short8v*)(bsw + (tp + 64) * BSTRIDE + kq * 8) = u1.s;
        }
    }

    // C/D layout (m89): col = lane&15, row = quad*4 + reg
    float* outB = out + (size_t)b * MDIM * TDIM;
    int rbase = mt * BM + wm * 64;
    int cbase = tt * BN + wn * 64;
#pragma unroll
    for (int i = 0; i < 4; ++i) {
#pragma unroll
        for (int j = 0; j < 4; ++j) {
            int row0 = rbase + i * 16 + quad * 4;
            int col = cbase + j * 16 + l16;
#pragma unroll
            for (int r = 0; r < 4; ++r)
                outB[(size_t)(row0 + r) * TDIM + col] = acc[i][j][r];
        }
    }
}

// ---------------------------------------------------------------------------
extern "C" void kernel_launch(void* const* d_in, const int* in_sizes, int n_in,
                              void* d_out, int out_size, void* d_ws, size_t ws_size,
                              hipStream_t stream) {
    const float* x = (const float*)d_in[0];      // (64,32,24,512) fp32
    const float* adj = (const float*)d_in[1];    // (24,24) fp32
    const float* Theta = (const float*)d_in[2];  // (3,32,32) fp32
    float* out = (float*)d_out;                  // (64,32,24,512) fp32

    // ws: WF fragment-ordered bf16 (1.18 MB)
    unsigned short* WF = (unsigned short*)d_ws;

    prep_w<<<64, 256, 0, stream>>>(adj, Theta, WF);
    gemm_fused<<<NMT * NTT * BATCH, 256, 0, stream>>>(WF, x, out);
}